// Round 4
// baseline (206.354 us; speedup 1.0000x reference)
//
#include <hip/hip_runtime.h>
#include <math.h>

// Problem constants (GeoFormer.generate_proposal, ScanNet config)
#define BB 4
#define QQ 128
#define NN 50000
#define CC 20
#define ROWS (BB * QQ)          // 512
#define NV4 (NN / 4)            // 12500 float4 per row
#define TPB 256
#define UNROLL 4
#define BPR 13                  // ceil(12500 / (256*4)) blocks per row
#define WPR 1568                // padded bitmask words per row (covers 50176 bits)
#define THRESH_CNT 50
#define MIN_CLS 4

// Native clang vector types — required for __builtin_nontemporal_store
typedef float f32x4 __attribute__((ext_vector_type(4)));
typedef int   i32x4 __attribute__((ext_vector_type(4)));

// Workspace header (re-initialized by k0 every call; harness poisons ws 0xAA).
// Bitmask (ROWS*WPR uint32 = 3.2 MB) follows the header in d_ws.
struct Ws {
    float sum[ROWS];
    int   cnt[ROWS];
    int   cls[ROWS];
    int   valid[ROWS];
};

// K0: per-(b,q) argmax over C=20 class logits (jnp.argmax tie-break = first
// max, i.e. strict '>' forward scan), and zero the accumulators.
__global__ void k0_argmax_zero(const float* __restrict__ cls_logits, Ws* ws) {
    int r = blockIdx.x * blockDim.x + threadIdx.x;
    if (r >= ROWS) return;
    const float* p = cls_logits + r * CC;
    float best = p[0];
    int bi = 0;
    #pragma unroll
    for (int c = 1; c < CC; ++c) {
        float v = p[c];
        if (v > best) { best = v; bi = c; }
    }
    ws->cls[r] = bi;
    ws->sum[r] = 0.0f;
    ws->cnt[r] = 0;
}

// ---------------- Main path: pure-read pack + pure-write expand -------------

// K1: PURE-READ pass. grid = (BPR, ROWS). Each thread owns 16 CONTIGUOUS
// elements (4 consecutive f32x4), computes 16 sel bits, pairs of lanes merge
// into one uint32 of the row bitmask. Also reduces cnt / sum-of-sigmoid.
__global__ __launch_bounds__(256) void k1_pack(
        const float* __restrict__ mask_logits,
        const int*   __restrict__ seg_pred,
        unsigned int* __restrict__ bits,
        Ws* __restrict__ ws) {
    const int row = blockIdx.y;          // 0..511  (b*Q + q)
    const int b   = row >> 7;            // row / Q
    const int cls = ws->cls[row];

    const f32x4* __restrict__ ml = (const f32x4*)mask_logits + (size_t)row * NV4;
    const i32x4* __restrict__ sp = (const i32x4*)seg_pred + b * NV4;

    // contiguous-per-thread: f32x4 indices base..base+3 (elements 16h..16h+15,
    // h = blockIdx.x*256 + tid)
    const int base = blockIdx.x * (TPB * UNROLL) + threadIdx.x * UNROLL;

    f32x4 v[UNROLL];
    i32x4 s[UNROLL];
    bool  act[UNROLL];
    #pragma unroll
    for (int j = 0; j < UNROLL; ++j) {
        act[j] = (base + j) < NV4;
        if (act[j]) {
            v[j] = ml[base + j];
            s[j] = sp[base + j];
        }
    }

    unsigned int b16 = 0;     // this thread's 16 sel bits
    float lsum = 0.0f;
    int   lcnt = 0;
    #pragma unroll
    for (int j = 0; j < UNROLL; ++j) {
        if (act[j]) {
            f32x4 vv = v[j];
            i32x4 ss = s[j];
            // sigmoid(x) > 0.5  <=>  x > 0
            unsigned s0 = (vv.x > 0.0f) & (ss.x == cls);
            unsigned s1 = (vv.y > 0.0f) & (ss.y == cls);
            unsigned s2 = (vv.z > 0.0f) & (ss.z == cls);
            unsigned s3 = (vv.w > 0.0f) & (ss.w == cls);
            b16 |= (s0 | (s1 << 1) | (s2 << 2) | (s3 << 3)) << (4 * j);
            float g0 = 1.0f / (1.0f + __expf(-vv.x));
            float g1 = 1.0f / (1.0f + __expf(-vv.y));
            float g2 = 1.0f / (1.0f + __expf(-vv.z));
            float g3 = 1.0f / (1.0f + __expf(-vv.w));
            lsum += (s0 ? g0 : 0.0f) + (s1 ? g1 : 0.0f)
                  + (s2 ? g2 : 0.0f) + (s3 ? g3 : 0.0f);
            lcnt += (int)(s0 + s1 + s2 + s3);
        }
    }

    // merge lane pairs: even lane holds final word (low 16 = own, high = odd)
    unsigned int partner = __shfl_xor((int)b16, 1);
    if ((threadIdx.x & 1) == 0) {
        unsigned int word = b16 | (partner << 16);
        const int h = blockIdx.x * TPB + threadIdx.x;  // halfword index
        const int w = h >> 1;
        if (w < WPR) bits[(size_t)row * WPR + w] = word;
    }

    // wave64 shuffle reduce (all threads participate — no early exits above)
    #pragma unroll
    for (int off = 32; off > 0; off >>= 1) {
        lsum += __shfl_down(lsum, off);
        lcnt += __shfl_down(lcnt, off);
    }
    __shared__ float ssum[4];
    __shared__ int   scnt[4];
    const int wave = threadIdx.x >> 6;
    const int lane = threadIdx.x & 63;
    if (lane == 0) { ssum[wave] = lsum; scnt[wave] = lcnt; }
    __syncthreads();
    if (threadIdx.x == 0) {
        float ts = ssum[0] + ssum[1] + ssum[2] + ssum[3];
        int   tc = scnt[0] + scnt[1] + scnt[2] + scnt[3];
        atomicAdd(&ws->sum[row], ts);
        atomicAdd(&ws->cnt[row], tc);
    }
}

// K_EXPAND: PURE-WRITE pass. grid = (BPR, ROWS). Reads the (L2-resident)
// bitmask, writes masks already gated by valid — replaces old k1-write + k3.
__global__ __launch_bounds__(256) void k_expand(
        const unsigned int* __restrict__ bits,
        const Ws* __restrict__ ws,
        float* __restrict__ out_mask) {
    const int row = blockIdx.y;
    const float on = ws->valid[row] ? 1.0f : 0.0f;
    const unsigned int* __restrict__ wb = bits + (size_t)row * WPR;
    f32x4* __restrict__ om = (f32x4*)out_mask + (size_t)row * NV4;
    const int idx0 = blockIdx.x * (TPB * UNROLL) + threadIdx.x;
    #pragma unroll
    for (int j = 0; j < UNROLL; ++j) {
        int idx = idx0 + j * TPB;
        if (idx < NV4) {
            unsigned int word = wb[idx >> 3];
            unsigned int nib = word >> ((idx & 7) * 4);
            f32x4 o;
            o.x = (nib & 1u) ? on : 0.0f;
            o.y = (nib & 2u) ? on : 0.0f;
            o.z = (nib & 4u) ? on : 0.0f;
            o.w = (nib & 8u) ? on : 0.0f;
            __builtin_nontemporal_store(o, &om[idx]);
        }
    }
}

// K2: finalize per-row outputs (scores, valid, cls_pred) + global_ids copy.
__global__ void k2_finalize_gids(const int* __restrict__ fg,
                                 float* __restrict__ out,
                                 Ws* __restrict__ ws) {
    const int idx = blockIdx.x * blockDim.x + threadIdx.x;
    if (idx < ROWS) {
        int   cnt = ws->cnt[idx];
        int   cls = ws->cls[idx];
        float sum = ws->sum[idx];
        int valid = (cnt >= THRESH_CNT) && (cls >= MIN_CLS);
        ws->valid[idx] = valid;
        float* tail = out + (size_t)ROWS * NN;
        tail[idx]            = valid ? (sum / (float)max(cnt, 1)) : 0.0f;  // scores
        tail[ROWS + idx]     = valid ? 1.0f : 0.0f;                        // valid
        tail[2 * ROWS + idx] = (float)cls;                                 // cls_pred
    }
    const int nv4 = (BB * NN) / 4;   // 50000
    if (idx < nv4) {
        float* gids = out + (size_t)ROWS * NN + 3 * ROWS;
        i32x4 v = ((const i32x4*)fg)[idx];
        f32x4 o;
        o.x = (float)v.x; o.y = (float)v.y; o.z = (float)v.z; o.w = (float)v.w;
        __builtin_nontemporal_store(o, &((f32x4*)gids)[idx]);
    }
}

// ---------------- Fallback path (ws too small): round-3 fused kernels ------

__global__ __launch_bounds__(256) void k1_select_fused(
        const float* __restrict__ mask_logits,
        const int*   __restrict__ seg_pred,
        float* __restrict__ out_mask,
        Ws* __restrict__ ws) {
    const int row = blockIdx.y;
    const int b   = row >> 7;
    const int cls = ws->cls[row];
    const f32x4* __restrict__ ml = (const f32x4*)(mask_logits + (size_t)row * NN);
    const i32x4* __restrict__ sp = (const i32x4*)(seg_pred + b * NN);
    f32x4* __restrict__ om = (f32x4*)(out_mask + (size_t)row * NN);
    const int idx0 = blockIdx.x * (TPB * UNROLL) + threadIdx.x;
    float lsum = 0.0f;
    int   lcnt = 0;
    #pragma unroll
    for (int j = 0; j < UNROLL; ++j) {
        int idx = idx0 + j * TPB;
        if (idx >= NV4) continue;
        f32x4 vv = ml[idx];
        i32x4 ss = sp[idx];
        bool s0 = (vv.x > 0.0f) & (ss.x == cls);
        bool s1 = (vv.y > 0.0f) & (ss.y == cls);
        bool s2 = (vv.z > 0.0f) & (ss.z == cls);
        bool s3 = (vv.w > 0.0f) & (ss.w == cls);
        f32x4 o;
        o.x = s0 ? 1.0f : 0.0f;
        o.y = s1 ? 1.0f : 0.0f;
        o.z = s2 ? 1.0f : 0.0f;
        o.w = s3 ? 1.0f : 0.0f;
        lsum += (s0 ? 1.0f / (1.0f + __expf(-vv.x)) : 0.0f)
              + (s1 ? 1.0f / (1.0f + __expf(-vv.y)) : 0.0f)
              + (s2 ? 1.0f / (1.0f + __expf(-vv.z)) : 0.0f)
              + (s3 ? 1.0f / (1.0f + __expf(-vv.w)) : 0.0f);
        lcnt += (int)s0 + (int)s1 + (int)s2 + (int)s3;
        __builtin_nontemporal_store(o, &om[idx]);
    }
    #pragma unroll
    for (int off = 32; off > 0; off >>= 1) {
        lsum += __shfl_down(lsum, off);
        lcnt += __shfl_down(lcnt, off);
    }
    __shared__ float ssum[4];
    __shared__ int   scnt[4];
    const int wave = threadIdx.x >> 6;
    const int lane = threadIdx.x & 63;
    if (lane == 0) { ssum[wave] = lsum; scnt[wave] = lcnt; }
    __syncthreads();
    if (threadIdx.x == 0) {
        atomicAdd(&ws->sum[row], ssum[0] + ssum[1] + ssum[2] + ssum[3]);
        atomicAdd(&ws->cnt[row], scnt[0] + scnt[1] + scnt[2] + scnt[3]);
    }
}

__global__ __launch_bounds__(256) void k3_fixup(
        float* __restrict__ out_mask, const Ws* __restrict__ ws) {
    const int row = blockIdx.y;
    if (ws->valid[row]) return;
    f32x4* __restrict__ om = (f32x4*)(out_mask + (size_t)row * NN);
    const f32x4 z = {0.0f, 0.0f, 0.0f, 0.0f};
    const int idx0 = blockIdx.x * (TPB * UNROLL) + threadIdx.x;
    #pragma unroll
    for (int j = 0; j < UNROLL; ++j) {
        int idx = idx0 + j * TPB;
        if (idx < NV4) __builtin_nontemporal_store(z, &om[idx]);
    }
}

extern "C" void kernel_launch(void* const* d_in, const int* in_sizes, int n_in,
                              void* d_out, int out_size, void* d_ws, size_t ws_size,
                              hipStream_t stream) {
    const float* mask_logits = (const float*)d_in[0];   // [B,Q,N] f32
    const float* cls_logits  = (const float*)d_in[1];   // [B,Q,C] f32
    const int*   seg_pred    = (const int*)d_in[2];     // [B,N]   int
    const int*   fg_idxs     = (const int*)d_in[3];     // [B*N]   int

    float* out = (float*)d_out;
    Ws* ws = (Ws*)d_ws;
    unsigned int* bits = (unsigned int*)((char*)d_ws + sizeof(Ws));

    // Output layout (flat, return order):
    //   [0, ROWS*NN)  proposal_masks | [+ROWS) scores | [+ROWS) valid
    //   [+ROWS) cls_pred | [+BB*NN) global_ids
    float* out_mask = out;

    const size_t ws_needed = sizeof(Ws) + (size_t)ROWS * WPR * sizeof(unsigned int);
    const bool use_split = (ws_size >= ws_needed);   // constant across calls

    k0_argmax_zero<<<(ROWS + 255) / 256, 256, 0, stream>>>(cls_logits, ws);

    dim3 g1(BPR, ROWS);
    const int gids_blocks = ((BB * NN) / 4 + 255) / 256;   // covers ROWS too

    if (use_split) {
        k1_pack<<<g1, TPB, 0, stream>>>(mask_logits, seg_pred, bits, ws);
        k2_finalize_gids<<<gids_blocks, 256, 0, stream>>>(fg_idxs, out, ws);
        k_expand<<<g1, TPB, 0, stream>>>(bits, ws, out_mask);
    } else {
        k1_select_fused<<<g1, TPB, 0, stream>>>(mask_logits, seg_pred, out_mask, ws);
        k2_finalize_gids<<<gids_blocks, 256, 0, stream>>>(fg_idxs, out, ws);
        k3_fixup<<<g1, TPB, 0, stream>>>(out_mask, ws);
    }
}

// Round 5
// 198.889 us; speedup vs baseline: 1.0375x; 1.0375x over previous
//
#include <hip/hip_runtime.h>
#include <math.h>

// Problem constants (GeoFormer.generate_proposal, ScanNet config)
#define BB 4
#define QQ 128
#define NN 50000
#define CC 20
#define ROWS (BB * QQ)          // 512
#define NV4 (NN / 4)            // 12500 float4 per row
#define TPB 256
#define UNROLL 4
#define BPR 13                  // ceil(12500 / (256*4)) blocks per row
#define W32 1568                // padded 32-bit words per row (covers 50176 bits)
#define THRESH_CNT 50
#define MIN_CLS 4

// Native clang vector types — required for __builtin_nontemporal_store
typedef float f32x4 __attribute__((ext_vector_type(4)));
typedef int   i32x4 __attribute__((ext_vector_type(4)));

// Workspace header (k0 re-inits every call; harness poisons ws with 0xAA).
// Layout: Ws | selbits[ROWS*W32] (3.21 MB) | classbit[BB*CC*W32] (0.50 MB)
struct Ws {
    float sum[ROWS];
    int   cnt[ROWS];
    int   cls[ROWS];
    int   valid[ROWS];
};

// K0: per-(b,q) argmax over C=20 class logits (jnp.argmax tie-break = first
// max, i.e. strict '>' forward scan), and zero the accumulators.
__global__ void k0_argmax_zero(const float* __restrict__ cls_logits, Ws* ws) {
    int r = blockIdx.x * blockDim.x + threadIdx.x;
    if (r >= ROWS) return;
    const float* p = cls_logits + r * CC;
    float best = p[0];
    int bi = 0;
    #pragma unroll
    for (int c = 1; c < CC; ++c) {
        float v = p[c];
        if (v > best) { best = v; bi = c; }
    }
    ws->cls[r] = bi;
    ws->sum[r] = 0.0f;
    ws->cnt[r] = 0;
}

// K_PRE: build per-class point bitmask classbit[b][c][w]: bit (p%32) of word
// p/32 = (seg_pred[b][p] == c). Read 0.8 MB once; k1 then reads 1 bit/elem
// instead of re-reading 4 B/elem of seg Q=128 times (102.4 MB -> 3.2 MB).
__global__ void k_pre_classbit(const int* __restrict__ seg,
                               unsigned int* __restrict__ classbit) {
    const int b = blockIdx.y;
    const int p = blockIdx.x * TPB + threadIdx.x;     // point id
    const int lane = threadIdx.x & 63;
    const int cl = (p < NN) ? seg[b * NN + p] : -1;
    // first 32-bit word of this wave's 64-point span
    const int w0 = (blockIdx.x * TPB + (threadIdx.x & ~63)) >> 5;
    #pragma unroll
    for (int c = 0; c < CC; ++c) {
        unsigned long long m = __ballot(cl == c);
        if (lane == 0)
            classbit[((size_t)b * CC + c) * W32 + w0]     = (unsigned int)m;
        if (lane == 32)
            classbit[((size_t)b * CC + c) * W32 + w0 + 1] = (unsigned int)(m >> 32);
    }
}

// K1: PURE-READ pass, lane-coalesced. grid = (BPR, ROWS). Reads mask_logits
// (f32x4) + the row's class bitmask; emits sel bitmask (selbits) + per-row
// cnt / sum-of-sigmoid. Load volume: 102.4 MB mask + ~3.2 MB bits.
__global__ __launch_bounds__(256) void k1_pack(
        const float* __restrict__ mask_logits,
        const unsigned int* __restrict__ classbit,
        unsigned int* __restrict__ selbits,
        Ws* __restrict__ ws) {
    const int row = blockIdx.y;          // 0..511  (b*Q + q)
    const int b   = row >> 7;            // row / Q
    const int cls = ws->cls[row];

    const unsigned int* __restrict__ cb = classbit + ((size_t)b * CC + cls) * W32;
    const f32x4* __restrict__ ml = (const f32x4*)mask_logits + (size_t)row * NV4;

    const int tid = threadIdx.x;
    const f32x4 vz = {0.0f, 0.0f, 0.0f, 0.0f};

    f32x4        v[UNROLL];
    unsigned int cw[UNROLL];
    int          idx[UNROLL];
    #pragma unroll
    for (int j = 0; j < UNROLL; ++j) {
        idx[j] = blockIdx.x * (TPB * UNROLL) + j * TPB + tid;  // lane-coalesced
        bool a = idx[j] < NV4;
        v[j]  = a ? ml[idx[j]] : vz;          // 0>0 false -> sel bits 0
        cw[j] = a ? cb[idx[j] >> 3] : 0u;
    }

    float lsum = 0.0f;
    int   lcnt = 0;
    #pragma unroll
    for (int j = 0; j < UNROLL; ++j) {
        f32x4 vv = v[j];
        // bit c of nib corresponds to element 4*idx+c; (idx&7)==(tid&7) since
        // block/j offsets are multiples of 8
        unsigned int nib = (cw[j] >> ((tid & 7) * 4)) & 0xFu;
        unsigned int se = ((vv.x > 0.0f) ? 1u : 0u) | ((vv.y > 0.0f) ? 2u : 0u)
                        | ((vv.z > 0.0f) ? 4u : 0u) | ((vv.w > 0.0f) ? 8u : 0u);
        unsigned int sel = se & nib;          // sigmoid(x)>0.5 <=> x>0
        lsum += ((sel & 1u) ? 1.0f / (1.0f + __expf(-vv.x)) : 0.0f)
              + ((sel & 2u) ? 1.0f / (1.0f + __expf(-vv.y)) : 0.0f)
              + ((sel & 4u) ? 1.0f / (1.0f + __expf(-vv.z)) : 0.0f)
              + ((sel & 8u) ? 1.0f / (1.0f + __expf(-vv.w)) : 0.0f);
        lcnt += __popc(sel);

        // merge 8 lanes' nibbles into one 32-bit word (OR-butterfly in-group)
        unsigned int w = sel << (4 * (tid & 7));
        w |= (unsigned int)__shfl_xor((int)w, 1);
        w |= (unsigned int)__shfl_xor((int)w, 2);
        w |= (unsigned int)__shfl_xor((int)w, 4);
        if ((tid & 7) == 0) {
            int wi = idx[j] >> 3;
            if (wi < W32) selbits[(size_t)row * W32 + wi] = w;
        }
    }

    // wave64 shuffle reduce (all lanes live — no divergence above)
    #pragma unroll
    for (int off = 32; off > 0; off >>= 1) {
        lsum += __shfl_down(lsum, off);
        lcnt += __shfl_down(lcnt, off);
    }
    __shared__ float ssum[4];
    __shared__ int   scnt[4];
    const int wave = tid >> 6;
    const int lane = tid & 63;
    if (lane == 0) { ssum[wave] = lsum; scnt[wave] = lcnt; }
    __syncthreads();
    if (tid == 0) {
        atomicAdd(&ws->sum[row], ssum[0] + ssum[1] + ssum[2] + ssum[3]);
        atomicAdd(&ws->cnt[row], scnt[0] + scnt[1] + scnt[2] + scnt[3]);
    }
}

// K2: finalize per-row outputs (scores, valid, cls_pred) + global_ids copy.
__global__ void k2_finalize_gids(const int* __restrict__ fg,
                                 float* __restrict__ out,
                                 Ws* __restrict__ ws) {
    const int idx = blockIdx.x * blockDim.x + threadIdx.x;
    if (idx < ROWS) {
        int   cnt = ws->cnt[idx];
        int   cls = ws->cls[idx];
        float sum = ws->sum[idx];
        int valid = (cnt >= THRESH_CNT) && (cls >= MIN_CLS);
        ws->valid[idx] = valid;
        float* tail = out + (size_t)ROWS * NN;
        tail[idx]            = valid ? (sum / (float)max(cnt, 1)) : 0.0f;  // scores
        tail[ROWS + idx]     = valid ? 1.0f : 0.0f;                        // valid
        tail[2 * ROWS + idx] = (float)cls;                                 // cls_pred
    }
    const int nv4 = (BB * NN) / 4;   // 50000
    if (idx < nv4) {
        float* gids = out + (size_t)ROWS * NN + 3 * ROWS;
        i32x4 v = ((const i32x4*)fg)[idx];
        f32x4 o;
        o.x = (float)v.x; o.y = (float)v.y; o.z = (float)v.z; o.w = (float)v.w;
        __builtin_nontemporal_store(o, &((f32x4*)gids)[idx]);
    }
}

// K_EXPAND: PURE-WRITE pass. grid = (BPR, ROWS). Reads L2-resident selbits,
// writes masks gated by valid (replaces separate fix-up pass).
__global__ __launch_bounds__(256) void k_expand(
        const unsigned int* __restrict__ selbits,
        const Ws* __restrict__ ws,
        float* __restrict__ out_mask) {
    const int row = blockIdx.y;
    const float on = ws->valid[row] ? 1.0f : 0.0f;
    const unsigned int* __restrict__ wb = selbits + (size_t)row * W32;
    f32x4* __restrict__ om = (f32x4*)out_mask + (size_t)row * NV4;
    const int idx0 = blockIdx.x * (TPB * UNROLL) + threadIdx.x;
    #pragma unroll
    for (int j = 0; j < UNROLL; ++j) {
        int idx = idx0 + j * TPB;
        if (idx < NV4) {
            unsigned int word = wb[idx >> 3];
            unsigned int nib = word >> ((idx & 7) * 4);
            f32x4 o;
            o.x = (nib & 1u) ? on : 0.0f;
            o.y = (nib & 2u) ? on : 0.0f;
            o.z = (nib & 4u) ? on : 0.0f;
            o.w = (nib & 8u) ? on : 0.0f;
            __builtin_nontemporal_store(o, &om[idx]);
        }
    }
}

// ---------------- Fallback path (ws too small): fused kernels ---------------

__global__ __launch_bounds__(256) void k1_select_fused(
        const float* __restrict__ mask_logits,
        const int*   __restrict__ seg_pred,
        float* __restrict__ out_mask,
        Ws* __restrict__ ws) {
    const int row = blockIdx.y;
    const int b   = row >> 7;
    const int cls = ws->cls[row];
    const f32x4* __restrict__ ml = (const f32x4*)(mask_logits + (size_t)row * NN);
    const i32x4* __restrict__ sp = (const i32x4*)(seg_pred + b * NN);
    f32x4* __restrict__ om = (f32x4*)(out_mask + (size_t)row * NN);
    const int idx0 = blockIdx.x * (TPB * UNROLL) + threadIdx.x;
    float lsum = 0.0f;
    int   lcnt = 0;
    #pragma unroll
    for (int j = 0; j < UNROLL; ++j) {
        int idx = idx0 + j * TPB;
        if (idx >= NV4) continue;
        f32x4 vv = ml[idx];
        i32x4 ss = sp[idx];
        bool s0 = (vv.x > 0.0f) & (ss.x == cls);
        bool s1 = (vv.y > 0.0f) & (ss.y == cls);
        bool s2 = (vv.z > 0.0f) & (ss.z == cls);
        bool s3 = (vv.w > 0.0f) & (ss.w == cls);
        f32x4 o;
        o.x = s0 ? 1.0f : 0.0f;
        o.y = s1 ? 1.0f : 0.0f;
        o.z = s2 ? 1.0f : 0.0f;
        o.w = s3 ? 1.0f : 0.0f;
        lsum += (s0 ? 1.0f / (1.0f + __expf(-vv.x)) : 0.0f)
              + (s1 ? 1.0f / (1.0f + __expf(-vv.y)) : 0.0f)
              + (s2 ? 1.0f / (1.0f + __expf(-vv.z)) : 0.0f)
              + (s3 ? 1.0f / (1.0f + __expf(-vv.w)) : 0.0f);
        lcnt += (int)s0 + (int)s1 + (int)s2 + (int)s3;
        __builtin_nontemporal_store(o, &om[idx]);
    }
    #pragma unroll
    for (int off = 32; off > 0; off >>= 1) {
        lsum += __shfl_down(lsum, off);
        lcnt += __shfl_down(lcnt, off);
    }
    __shared__ float ssum[4];
    __shared__ int   scnt[4];
    const int wave = threadIdx.x >> 6;
    const int lane = threadIdx.x & 63;
    if (lane == 0) { ssum[wave] = lsum; scnt[wave] = lcnt; }
    __syncthreads();
    if (threadIdx.x == 0) {
        atomicAdd(&ws->sum[row], ssum[0] + ssum[1] + ssum[2] + ssum[3]);
        atomicAdd(&ws->cnt[row], scnt[0] + scnt[1] + scnt[2] + scnt[3]);
    }
}

__global__ __launch_bounds__(256) void k3_fixup(
        float* __restrict__ out_mask, const Ws* __restrict__ ws) {
    const int row = blockIdx.y;
    if (ws->valid[row]) return;
    f32x4* __restrict__ om = (f32x4*)(out_mask + (size_t)row * NN);
    const f32x4 z = {0.0f, 0.0f, 0.0f, 0.0f};
    const int idx0 = blockIdx.x * (TPB * UNROLL) + threadIdx.x;
    #pragma unroll
    for (int j = 0; j < UNROLL; ++j) {
        int idx = idx0 + j * TPB;
        if (idx < NV4) __builtin_nontemporal_store(z, &om[idx]);
    }
}

extern "C" void kernel_launch(void* const* d_in, const int* in_sizes, int n_in,
                              void* d_out, int out_size, void* d_ws, size_t ws_size,
                              hipStream_t stream) {
    const float* mask_logits = (const float*)d_in[0];   // [B,Q,N] f32
    const float* cls_logits  = (const float*)d_in[1];   // [B,Q,C] f32
    const int*   seg_pred    = (const int*)d_in[2];     // [B,N]   int
    const int*   fg_idxs     = (const int*)d_in[3];     // [B*N]   int

    float* out = (float*)d_out;
    Ws* ws = (Ws*)d_ws;
    unsigned int* selbits  = (unsigned int*)((char*)d_ws + sizeof(Ws));
    unsigned int* classbit = selbits + (size_t)ROWS * W32;

    // Output layout (flat, return order):
    //   [0, ROWS*NN)  proposal_masks | [+ROWS) scores | [+ROWS) valid
    //   [+ROWS) cls_pred | [+BB*NN) global_ids
    float* out_mask = out;

    const size_t ws_needed = sizeof(Ws)
        + (size_t)ROWS * W32 * sizeof(unsigned int)
        + (size_t)BB * CC * W32 * sizeof(unsigned int);
    const bool use_split = (ws_size >= ws_needed);   // constant across calls

    k0_argmax_zero<<<(ROWS + 255) / 256, 256, 0, stream>>>(cls_logits, ws);

    dim3 g1(BPR, ROWS);
    const int gids_blocks = ((BB * NN) / 4 + 255) / 256;   // covers ROWS too

    if (use_split) {
        dim3 gp((NN + TPB - 1) / TPB, BB);   // (196, 4)
        k_pre_classbit<<<gp, TPB, 0, stream>>>(seg_pred, classbit);
        k1_pack<<<g1, TPB, 0, stream>>>(mask_logits, classbit, selbits, ws);
        k2_finalize_gids<<<gids_blocks, 256, 0, stream>>>(fg_idxs, out, ws);
        k_expand<<<g1, TPB, 0, stream>>>(selbits, ws, out_mask);
    } else {
        k1_select_fused<<<g1, TPB, 0, stream>>>(mask_logits, seg_pred, out_mask, ws);
        k2_finalize_gids<<<gids_blocks, 256, 0, stream>>>(fg_idxs, out, ws);
        k3_fixup<<<g1, TPB, 0, stream>>>(out_mask, ws);
    }
}